// Round 3
// baseline (227.094 us; speedup 1.0000x reference)
//
#include <hip/hip_runtime.h>
#include <cfloat>

// ---------------------------------------------------------------------------
// VectorQuantizer: z (16,256,32,32) f32, codebook (8192,256) f32
// outputs (f32 concat): z_q [4194304], loss [1], idx-as-float [16384]
// Validated semantics (R2-R6): idx = argmin_k fl32(zsq - 2*dot32(z,e_k)),
// lowest-index tie-break; bf16-MFMA coarse top-4 x 8 slices -> 32 cands/row;
// prune to coarse margin of row max; survivors re-scored fp64->fp32.
// R7-R9: argmin pipeline (async LDS staging, 64 z-rows/wave, tagged-float
// epilogue, counted-vmcnt tri-buffer). R8/R9 nulls proved argmin is pinned
// at ~70us by 2-waves/SIMD structure (B-residency = 128 VGPR) — left as-is.
// R10: attack the unprofiled ~114us outside argmin:
//   - zq rewritten: 1024 blocks (4/CU, was 1/CU latency-bound), 16 rows/blk,
//     cb staged transposed [c][16r]+pad, pure float4 gather->scatter, no z
//     read (loss removed) -> 32 MB traffic, ~6-8us.
//   - loss computed in fixup (already stages z as exact f64 + knows idx):
//     per-block f64 partial -> atomicAdd(double) on scratch in dead region
//     + ticket; last block writes f32 loss. More accurate than old f32
//     atomic chain. prep zeroes scratch/ticket each replay.
// ---------------------------------------------------------------------------

#define NROWS 16384
#define NCODE 8192
#define DIMC  256
#define HW    1024
#define ZQN   4194304

// scratch inside d_out's z_q region (dead before zq_kernel overwrites):
#define ZT_OFF   0         // bf16 z*2^21 [16384][256] as ushort = 2097152 floats
#define CBT_OFF  2097152   // bf16 codebook [8192][256]          = 1048576 floats
#define ZSQ_OFF  3145728   // 16384 floats
#define CAND_OFF 3162112   // 8 slices * 16384 rows * 4 packed uints -> ends 3686400
#define SCR_OFF  3686400   // f64 loss accumulator (2 floats, 8B-aligned)
#define TKT_OFF  3686402   // ticket uint
#define LOSS_OFF ZQN
#define IDX_OFF  (ZQN + 1)

#define NSLICE 8
#define PRUNE_T 4300u      // key units (8 float-ulps each, worst 1.49e-8 dot):
                           // covers d-bin 3.05e-5 + 2x6sigma bf16 + tag-quant
#define ZSCALE 2097152.0f  // 2^21, exact in bf16/f32

typedef __attribute__((ext_vector_type(8))) short bf16x8;
typedef __attribute__((ext_vector_type(4))) float f32x4;
typedef __attribute__((ext_vector_type(4))) unsigned int uint4v;

__device__ __forceinline__ unsigned umax(unsigned a, unsigned b) { return a > b ? a : b; }
__device__ __forceinline__ unsigned umin(unsigned a, unsigned b) { return a < b ? a : b; }

__device__ __forceinline__ unsigned short f2bf(float f) {   // RNE
    unsigned u = __float_as_uint(f);
    return (unsigned short)((u + 0x7fffu + ((u >> 16) & 1u)) >> 16);
}

#define GLD_LDS16(gptr, lptr) \
  __builtin_amdgcn_global_load_lds((const __attribute__((address_space(1))) unsigned int*)(const void*)(gptr), \
                                   (__attribute__((address_space(3))) unsigned int*)(lptr), 16, 0, 0)

// --- 1: fused prep: zt transpose+cvt(*2^21) | cbt cvt | zsq | scratch zero -
__global__ void prep_kernel(const float* __restrict__ z, const float* __restrict__ cb,
                            float* __restrict__ out) {
    int bid = blockIdx.x;
    int tid = threadIdx.x;
    if (bid < 1024) {
        __shared__ unsigned short lds[64 * 65];
        unsigned short* zt = (unsigned short*)(out + ZT_OFF);
        int c0 = (bid & 3) * 64;
        int n0 = (bid >> 2) * 64;
        const float* zb = z + (size_t)(n0 >> 10) * (DIMC * HW) + (n0 & 1023);
        #pragma unroll
        for (int i = 0; i < 4; ++i) {
            int f = tid + i * 256;
            int cl = f >> 4, n4 = f & 15;
            float4 v = *(const float4*)(zb + (size_t)(c0 + cl) * HW + n4 * 4);
            lds[(n4 * 4 + 0) * 65 + cl] = f2bf(v.x * ZSCALE);
            lds[(n4 * 4 + 1) * 65 + cl] = f2bf(v.y * ZSCALE);
            lds[(n4 * 4 + 2) * 65 + cl] = f2bf(v.z * ZSCALE);
            lds[(n4 * 4 + 3) * 65 + cl] = f2bf(v.w * ZSCALE);
        }
        __syncthreads();
        #pragma unroll
        for (int i = 0; i < 2; ++i) {
            int f = tid + i * 256;
            int nl = f >> 3, oct = f & 7;
            const unsigned short* p = lds + nl * 65 + oct * 8;
            uint4v u;
            u.x = (unsigned)p[0] | ((unsigned)p[1] << 16);
            u.y = (unsigned)p[2] | ((unsigned)p[3] << 16);
            u.z = (unsigned)p[4] | ((unsigned)p[5] << 16);
            u.w = (unsigned)p[6] | ((unsigned)p[7] << 16);
            *(uint4v*)(zt + (size_t)(n0 + nl) * DIMC + c0 + oct * 8) = u;
        }
    } else if (bid < 2048) {
        unsigned short* cbt = (unsigned short*)(out + CBT_OFF);
        size_t t = (size_t)(bid - 1024) * 256 + tid;
        float4 a = *(const float4*)(cb + t * 8);
        float4 b = *(const float4*)(cb + t * 8 + 4);
        uint4v u;
        u.x = (unsigned)f2bf(a.x) | ((unsigned)f2bf(a.y) << 16);
        u.y = (unsigned)f2bf(a.z) | ((unsigned)f2bf(a.w) << 16);
        u.z = (unsigned)f2bf(b.x) | ((unsigned)f2bf(b.y) << 16);
        u.w = (unsigned)f2bf(b.z) | ((unsigned)f2bf(b.w) << 16);
        *(uint4v*)(cbt + t * 8) = u;
        if (bid == 1024 && tid == 0) {
            out[LOSS_OFF] = 0.0f;
            out[SCR_OFF] = 0.0f;          // f64 loss accumulator (2 floats)
            out[SCR_OFF + 1] = 0.0f;
            ((unsigned*)out)[TKT_OFF] = 0u;   // ticket
        }
    } else {
        int n = (bid - 2048) * 256 + tid;
        const float* zp = z + (size_t)(n >> 10) * (DIMC * HW) + (n & 1023);
        double s = 0.0;
        for (int c = 0; c < DIMC; ++c) {
            double v = (double)zp[(size_t)c * HW];
            s += v * v;
        }
        out[ZSQ_OFF + n] = (float)s;
    }
}

// --- 2: bf16 MFMA argmin: counted-vmcnt triple-buffer pipeline (R9) --------
// grid (64 row-blocks, 8 slices), 256 threads. Block: 256 rows x 1024 codes.
__global__ __launch_bounds__(256, 2)
void argmin_kernel(float* __restrict__ out) {
    __shared__ __align__(16) unsigned short a_s[3 * 8192];   // 48 KB, 3 bufs
    const unsigned short* zt  = (const unsigned short*)(out + ZT_OFF);
    const unsigned short* cbt = (const unsigned short*)(out + CBT_OFF);
    unsigned* cand = (unsigned*)(out + CAND_OFF);

    int tid = threadIdx.x;
    int lane = tid & 63;
    int wv = tid >> 6;
    int col = lane & 15, qk = lane >> 4;
    int n0 = blockIdx.x * 256;
    int slice = blockIdx.y;

    // B: wave's 64 z-rows (pre-scaled by 2^21) resident in registers
    bf16x8 B[4][8];
    #pragma unroll
    for (int rf = 0; rf < 4; ++rf)
        #pragma unroll
        for (int t = 0; t < 8; ++t)
            B[rf][t] = *(const bf16x8*)(zt + (size_t)(n0 + wv * 64 + rf * 16 + col) * DIMC
                                           + t * 32 + qk * 8);

    // staging sources: lane covers (row pair, 16B slot); XOR swizzle
    int rl2 = lane >> 5;
    int jsl = lane & 31;
    const unsigned short* srcb[4];
    #pragma unroll
    for (int c = 0; c < 4; ++c) {
        int rloc = (wv * 4 + c) * 2 + rl2;
        int src16 = jsl ^ (rloc & 7) ^ ((rloc & 8) >> 1);
        srcb[c] = cbt + ((size_t)slice * 1024 + rloc) * DIMC + src16 * 8;
    }

    unsigned U1[4] = {0, 0, 0, 0}, U2[4] = {0, 0, 0, 0};

    // chunk-invariant per-lane LDS read addresses (buf/cf via imm offset)
    const unsigned sb = (unsigned)((col & 7) ^ ((col & 8) >> 1));
    const unsigned short* aoff[8];
    #pragma unroll
    for (int t = 0; t < 8; ++t)
        aoff[t] = a_s + col * 256 + (((unsigned)(qk + 4 * t)) ^ sb) * 8;

    f32x4 acc[4][2];
    const f32x4 BIASV = (f32x4){131072.0f, 131072.0f, 131072.0f, 131072.0f};

    auto stage = [&](int ch, int dsto /*shorts*/) {
        const size_t off = (size_t)ch * 32 * DIMC;
        unsigned short* dst = a_s + dsto;
        #pragma unroll
        for (int c = 0; c < 4; ++c)
            GLD_LDS16(srcb[c] + off, dst + (wv * 4 + c) * 512);
    };

    // deferred epilogue: cf=1 scores of the PREVIOUS chunk (tag base tb)
    auto epi1 = [&](unsigned tb) {
        #pragma unroll
        for (int rf = 0; rf < 4; ++rf)
            #pragma unroll
            for (int r = 0; r < 4; ++r) {
                unsigned bits = __float_as_uint(acc[rf][1][r]);
                unsigned u = (bits & 0xFFFFFF00u) | (tb - (unsigned)(4 + r));
                unsigned lo = umin(u, U1[rf]);
                U1[rf] = umax(u, U1[rf]);
                U2[rf] = umax(lo, U2[rf]);
            }
    };

    // one chunk: cf0 MFMAs, then cf1 MFMAs with cf0 epilogue interleaved.
    auto compute = [&](int bufb, unsigned tb) {
        #pragma unroll
        for (int rf = 0; rf < 4; ++rf) acc[rf][0] = BIASV;
        #pragma unroll
        for (int t = 0; t < 8; ++t) {
            bf16x8 af = *(const bf16x8*)((const char*)aoff[t] + bufb);
            acc[0][0] = __builtin_amdgcn_mfma_f32_16x16x32_bf16(af, B[0][t], acc[0][0], 0, 0, 0);
            acc[1][0] = __builtin_amdgcn_mfma_f32_16x16x32_bf16(af, B[1][t], acc[1][0], 0, 0, 0);
            acc[2][0] = __builtin_amdgcn_mfma_f32_16x16x32_bf16(af, B[2][t], acc[2][0], 0, 0, 0);
            acc[3][0] = __builtin_amdgcn_mfma_f32_16x16x32_bf16(af, B[3][t], acc[3][0], 0, 0, 0);
        }
        #pragma unroll
        for (int rf = 0; rf < 4; ++rf) acc[rf][1] = BIASV;
        #pragma unroll
        for (int t = 0; t < 8; ++t) {
            bf16x8 af = *(const bf16x8*)((const char*)aoff[t] + bufb + 8192);
            acc[0][1] = __builtin_amdgcn_mfma_f32_16x16x32_bf16(af, B[0][t], acc[0][1], 0, 0, 0);
            acc[1][1] = __builtin_amdgcn_mfma_f32_16x16x32_bf16(af, B[1][t], acc[1][1], 0, 0, 0);
            acc[2][1] = __builtin_amdgcn_mfma_f32_16x16x32_bf16(af, B[2][t], acc[2][1], 0, 0, 0);
            acc[3][1] = __builtin_amdgcn_mfma_f32_16x16x32_bf16(af, B[3][t], acc[3][1], 0, 0, 0);
            {   // interleave: 2 cf0 scores of THIS chunk per t-step
                const int q0 = 2 * t, q1 = 2 * t + 1;
                const int rfA = q0 >> 2, rA = q0 & 3;
                const int rfB = q1 >> 2, rB = q1 & 3;
                unsigned bitsA = __float_as_uint(acc[rfA][0][rA]);
                unsigned uA = (bitsA & 0xFFFFFF00u) | (tb - (unsigned)rA);
                unsigned loA = umin(uA, U1[rfA]);
                U1[rfA] = umax(uA, U1[rfA]);
                U2[rfA] = umax(loA, U2[rfA]);
                unsigned bitsB = __float_as_uint(acc[rfB][0][rB]);
                unsigned uB = (bitsB & 0xFFFFFF00u) | (tb - (unsigned)rB);
                unsigned loB = umin(uB, U1[rfB]);
                U1[rfB] = umax(uB, U1[rfB]);
                U2[rfB] = umax(loB, U2[rfB]);
            }
        }
    };

#define CHUNK_SYNC(N)                                          \
    asm volatile("s_waitcnt vmcnt(" #N ")" ::: "memory");      \
    __builtin_amdgcn_s_barrier();                              \
    __builtin_amdgcn_sched_barrier(0);

    // prologue: stage chunks 0,1
    stage(0, 0);
    stage(1, 8192);

    CHUNK_SYNC(4)
    stage(2, 16384);
    compute(0, 255u);

    #pragma unroll 1
    for (int k = 0; k < 10; ++k) {
        const int c1 = 3 * k + 1;
        const unsigned tb = 255u - ((unsigned)c1 << 3);
        CHUNK_SYNC(4)
        stage(c1 + 2, 0);
        epi1(tb + 8u);
        compute(16384, tb);
        CHUNK_SYNC(4)
        stage(c1 + 3, 8192);
        epi1(tb);
        compute(32768, tb - 8u);
        CHUNK_SYNC(4)
        if (k < 9) stage(c1 + 4, 16384);
        epi1(tb - 8u);
        compute(0, tb - 16u);
    }
    CHUNK_SYNC(0)
    epi1(255u - (30u << 3));
    compute(16384, 255u - (31u << 3));
    epi1(255u - (31u << 3));
#undef CHUNK_SYNC

    // decode to (key22<<10 | 1023-local), cross-qk merge top-4, store packed
    #pragma unroll
    for (int rf = 0; rf < 4; ++rf) {
        unsigned t1 = 255u - (U1[rf] & 255u);
        unsigned c1 = (t1 >> 3) * 32 + ((t1 >> 2) & 1) * 16 + qk * 4 + (t1 & 3);
        unsigned x1 = ((((U1[rf] & 0xFFFFFF00u) - 0x47000000u) >> 3) << 10) | (1023u - c1);
        unsigned t2 = 255u - (U2[rf] & 255u);
        unsigned c2 = (t2 >> 3) * 32 + ((t2 >> 2) & 1) * 16 + qk * 4 + (t2 & 3);
        unsigned x2 = ((((U2[rf] & 0xFFFFFF00u) - 0x47000000u) >> 3) << 10) | (1023u - c2);
        unsigned p1 = __shfl_xor(x1, 16);
        unsigned p2 = __shfl_xor(x2, 16);
        unsigned s1 = umax(x1, p1), tm = umin(x1, p1);
        unsigned ym = umax(x2, p2), s4 = umin(x2, p2);
        unsigned s2 = umax(tm, ym), s3 = umin(tm, ym);
        unsigned r1 = umax(s1, __shfl_xor(s4, 32));
        unsigned r2 = umax(s2, __shfl_xor(s3, 32));
        unsigned r3 = umax(s3, __shfl_xor(s2, 32));
        unsigned r4 = umax(s4, __shfl_xor(s1, 32));
        if (qk == 0) {
            int row = wv * 64 + rf * 16 + col;
            uint4v cw; cw.x = r1; cw.y = r2; cw.z = r3; cw.w = r4;
            *(uint4v*)(cand + ((size_t)slice * NROWS + n0 + row) * 4) = cw;
        }
    }
}

// --- 3: prune + fp64 re-score survivors + fused loss ------------------------
// 2048 blocks x 256 threads; block = 8 rows x 32 candidates.
__global__ __launch_bounds__(256, 4)
void fixup_kernel(const float* __restrict__ z, const float* __restrict__ cb,
                  float* __restrict__ out) {
    __shared__ double zd[DIMC * 8];
    __shared__ float zsq_s[8];
    __shared__ unsigned qmx[8];
    __shared__ float dsc[32 * 8];
    __shared__ unsigned cds[32 * 8];
    __shared__ unsigned bcode[8];
    __shared__ double lred[4];
    int tid = threadIdx.x;
    int n0 = blockIdx.x * 8;
    const float* zb = z + (size_t)(n0 >> 10) * (DIMC * HW) + (n0 & 1023);
    int rr = tid & 7;
    #pragma unroll
    for (int i = 0; i < 8; ++i) {
        int c = (tid >> 3) + i * 32;
        zd[c * 8 + rr] = (double)zb[(size_t)c * HW + rr];
    }
    if (tid < 8) { zsq_s[tid] = out[ZSQ_OFF + n0 + tid]; qmx[tid] = 0; }
    int j = tid >> 3, r = tid & 7;
    unsigned w = ((const unsigned*)(out + CAND_OFF))
                 [(((size_t)(j >> 2)) * NROWS + n0 + r) * 4 + (j & 3)];
    unsigned qv = w >> 10;
    unsigned code = (unsigned)((j >> 2) * 1024) + 1023u - (w & 1023u);
    __syncthreads();
    atomicMax(&qmx[r], qv);
    __syncthreads();
    bool live = (qv + PRUNE_T >= qmx[r]);
    float d = FLT_MAX;
    if (live) {
        const float* e = cb + (size_t)code * DIMC;
        double a0 = 0.0, a1 = 0.0, a2 = 0.0, a3 = 0.0;
        for (int c = 0; c < DIMC; c += 16) {
            float4 e0 = *(const float4*)(e + c);
            float4 e1 = *(const float4*)(e + c + 4);
            float4 e2 = *(const float4*)(e + c + 8);
            float4 e3 = *(const float4*)(e + c + 12);
            a0 += zd[(c + 0) * 8 + r] * (double)e0.x + zd[(c + 1) * 8 + r] * (double)e0.y
                + zd[(c + 2) * 8 + r] * (double)e0.z + zd[(c + 3) * 8 + r] * (double)e0.w;
            a1 += zd[(c + 4) * 8 + r] * (double)e1.x + zd[(c + 5) * 8 + r] * (double)e1.y
                + zd[(c + 6) * 8 + r] * (double)e1.z + zd[(c + 7) * 8 + r] * (double)e1.w;
            a2 += zd[(c + 8) * 8 + r] * (double)e2.x + zd[(c + 9) * 8 + r] * (double)e2.y
                + zd[(c + 10) * 8 + r] * (double)e2.z + zd[(c + 11) * 8 + r] * (double)e2.w;
            a3 += zd[(c + 12) * 8 + r] * (double)e3.x + zd[(c + 13) * 8 + r] * (double)e3.y
                + zd[(c + 14) * 8 + r] * (double)e3.z + zd[(c + 15) * 8 + r] * (double)e3.w;
        }
        d = fmaf(-2.0f, (float)((a0 + a1) + (a2 + a3)), zsq_s[r]);
    }
    dsc[j * 8 + r] = d;
    cds[j * 8 + r] = code;
    __syncthreads();
    if (tid < 8) {
        float bd = FLT_MAX; unsigned bi = 0xffffffffu;
        for (int jj = 0; jj < 32; ++jj) {
            float dv = dsc[jj * 8 + tid];
            unsigned k = cds[jj * 8 + tid];
            if (dv < bd || (dv == bd && k < bi)) { bd = dv; bi = k; }
        }
        out[IDX_OFF + n0 + tid] = (float)bi;
        bcode[tid] = bi;
    }
    __syncthreads();
    // fused loss: (cb[idx_n][c] - z[n][c])^2 summed in f64. zd holds exact z.
    double zr[8];
    #pragma unroll
    for (int k = 0; k < 8; ++k) zr[k] = zd[tid * 8 + k];
    double lacc = 0.0;
    #pragma unroll
    for (int r8 = 0; r8 < 8; ++r8) {
        float e = cb[(size_t)bcode[r8] * DIMC + tid];
        double dd = (double)e - zr[r8];
        lacc += dd * dd;
    }
    #pragma unroll
    for (int off = 32; off; off >>= 1) lacc += __shfl_down(lacc, off);
    if ((tid & 63) == 0) lred[tid >> 6] = lacc;
    __syncthreads();
    if (tid == 0) {
        double part = (lred[0] + lred[1]) + (lred[2] + lred[3]);
        atomicAdd((double*)(out + SCR_OFF), part);
        __threadfence();
        unsigned t = atomicAdd(((unsigned*)out) + TKT_OFF, 1u);
        if (t == 2047u) {   // last block: all adds visible (fenced RMW chain)
            __threadfence();
            double tot = atomicAdd((double*)(out + SCR_OFF), 0.0);
            out[LOSS_OFF] = (float)(tot * (1.25 / 4194304.0));
        }
    }
}

// --- 4: z_q pure gather->scatter: 1024 blocks x 256 thr, 16 rows/block -----
__global__ __launch_bounds__(256)
void zq_kernel(const float* __restrict__ z, const float* __restrict__ cb,
               float* __restrict__ out) {
    __shared__ float lds[256 * 20];   // [c][r(16) + pad4]: <=2-way conflicts
    int tid = threadIdx.x;
    int n0 = blockIdx.x * 16;
    {   // gather 16 codebook rows, store transposed [c][r]
        int r = tid >> 4, q = tid & 15;
        int code = (int)out[IDX_OFF + n0 + r];
        const float* e = cb + (size_t)code * DIMC;
        #pragma unroll
        for (int jj = 0; jj < 4; ++jj) {
            int c = q * 4 + jj * 64;
            float4 v = *(const float4*)(e + c);
            lds[(c + 0) * 20 + r] = v.x;
            lds[(c + 1) * 20 + r] = v.y;
            lds[(c + 2) * 20 + r] = v.z;
            lds[(c + 3) * 20 + r] = v.w;
        }
    }
    __syncthreads();
    // scatter: thread = (c-group g, row-quad rq); float4 over 4 hw positions
    int g = tid >> 2, rq = tid & 3;
    int b = n0 >> 10, hw0 = n0 & 1023;
    const size_t base = (size_t)b * (DIMC * HW) + hw0 + rq * 4;
    #pragma unroll
    for (int i = 0; i < 4; ++i) {
        int c = g + i * 64;
        float4 v;
        v.x = lds[c * 20 + rq * 4 + 0];
        v.y = lds[c * 20 + rq * 4 + 1];
        v.z = lds[c * 20 + rq * 4 + 2];
        v.w = lds[c * 20 + rq * 4 + 3];
        *(float4*)(out + base + (size_t)c * HW) = v;
    }
}

extern "C" void kernel_launch(void* const* d_in, const int* in_sizes, int n_in,
                              void* d_out, int out_size, void* d_ws, size_t ws_size,
                              hipStream_t stream) {
    const float* z  = (const float*)d_in[0];
    const float* cb = (const float*)d_in[1];
    float* out = (float*)d_out;

    prep_kernel<<<2112, 256, 0, stream>>>(z, cb, out);
    argmin_kernel<<<dim3(64, NSLICE), 256, 0, stream>>>(out);
    fixup_kernel<<<NROWS / 8, 256, 0, stream>>>(z, cb, out);
    zq_kernel<<<1024, 256, 0, stream>>>(z, cb, out);
}

// Round 5
// 185.892 us; speedup vs baseline: 1.2216x; 1.2216x over previous
//
#include <hip/hip_runtime.h>
#include <cfloat>

// ---------------------------------------------------------------------------
// VectorQuantizer: z (16,256,32,32) f32, codebook (8192,256) f32
// outputs (f32 concat): z_q [4194304], loss [1], idx-as-float [16384]
// Validated semantics (R2-R6): idx = argmin_k fl32(zsq - 2*dot32(z,e_k)),
// lowest-index tie-break; bf16-MFMA coarse top-4 x 8 slices -> 32 cands/row;
// prune to coarse margin of row max; survivors re-scored fp64->fp32.
// R7-R9: argmin pipeline pinned at ~70us (2 waves/SIMD structural) — frozen.
// R10 post-mortem: fixup = 82us latency-bound (VALU 11%, HBM 7.6%);
//   __threadfence = L2 wb/inv storm; 8-row blocks -> 32B-segment z loads.
// R11: fixup v2: 512 blocks x 32 rows; z staged once as f32 [row][264] with
//   XOR-quad swizzle (write 2-way free, dot reads broadcast/disjoint-quads);
//   4 batches of the identical validated 8x32 re-score; loss fused on the
//   same tile; ticket finalize with s_waitcnt only (NO threadfence — atomic
//   RMW chains are ordered at the L2 coherence point). zq: [r][260] layout,
//   gather = direct b128 LDS writes, scatter column reads 2-way free.
// R12: resubmit of R11 (container infra failure, no kernel signal; audit
//   found no OOB/hang path).
// ---------------------------------------------------------------------------

#define NROWS 16384
#define NCODE 8192
#define DIMC  256
#define HW    1024
#define ZQN   4194304

// scratch inside d_out's z_q region (dead before zq_kernel overwrites):
#define ZT_OFF   0         // bf16 z*2^21 [16384][256] as ushort = 2097152 floats
#define CBT_OFF  2097152   // bf16 codebook [8192][256]          = 1048576 floats
#define ZSQ_OFF  3145728   // 16384 floats
#define CAND_OFF 3162112   // 8 slices * 16384 rows * 4 packed uints -> ends 3686400
#define SCR_OFF  3686400   // f64 loss accumulator (2 floats, 8B-aligned)
#define TKT_OFF  3686402   // ticket uint
#define LOSS_OFF ZQN
#define IDX_OFF  (ZQN + 1)

#define NSLICE 8
#define PRUNE_T 4300u      // key units (8 float-ulps each, worst 1.49e-8 dot):
                           // covers d-bin 3.05e-5 + 2x6sigma bf16 + tag-quant
#define ZSCALE 2097152.0f  // 2^21, exact in bf16/f32

typedef __attribute__((ext_vector_type(8))) short bf16x8;
typedef __attribute__((ext_vector_type(4))) float f32x4;
typedef __attribute__((ext_vector_type(4))) unsigned int uint4v;

__device__ __forceinline__ unsigned umax(unsigned a, unsigned b) { return a > b ? a : b; }
__device__ __forceinline__ unsigned umin(unsigned a, unsigned b) { return a < b ? a : b; }

__device__ __forceinline__ unsigned short f2bf(float f) {   // RNE
    unsigned u = __float_as_uint(f);
    return (unsigned short)((u + 0x7fffu + ((u >> 16) & 1u)) >> 16);
}

#define GLD_LDS16(gptr, lptr) \
  __builtin_amdgcn_global_load_lds((const __attribute__((address_space(1))) unsigned int*)(const void*)(gptr), \
                                   (__attribute__((address_space(3))) unsigned int*)(lptr), 16, 0, 0)

// --- 1: fused prep: zt transpose+cvt(*2^21) | cbt cvt | zsq | scratch zero -
__global__ void prep_kernel(const float* __restrict__ z, const float* __restrict__ cb,
                            float* __restrict__ out) {
    int bid = blockIdx.x;
    int tid = threadIdx.x;
    if (bid < 1024) {
        __shared__ unsigned short lds[64 * 65];
        unsigned short* zt = (unsigned short*)(out + ZT_OFF);
        int c0 = (bid & 3) * 64;
        int n0 = (bid >> 2) * 64;
        const float* zb = z + (size_t)(n0 >> 10) * (DIMC * HW) + (n0 & 1023);
        #pragma unroll
        for (int i = 0; i < 4; ++i) {
            int f = tid + i * 256;
            int cl = f >> 4, n4 = f & 15;
            float4 v = *(const float4*)(zb + (size_t)(c0 + cl) * HW + n4 * 4);
            lds[(n4 * 4 + 0) * 65 + cl] = f2bf(v.x * ZSCALE);
            lds[(n4 * 4 + 1) * 65 + cl] = f2bf(v.y * ZSCALE);
            lds[(n4 * 4 + 2) * 65 + cl] = f2bf(v.z * ZSCALE);
            lds[(n4 * 4 + 3) * 65 + cl] = f2bf(v.w * ZSCALE);
        }
        __syncthreads();
        #pragma unroll
        for (int i = 0; i < 2; ++i) {
            int f = tid + i * 256;
            int nl = f >> 3, oct = f & 7;
            const unsigned short* p = lds + nl * 65 + oct * 8;
            uint4v u;
            u.x = (unsigned)p[0] | ((unsigned)p[1] << 16);
            u.y = (unsigned)p[2] | ((unsigned)p[3] << 16);
            u.z = (unsigned)p[4] | ((unsigned)p[5] << 16);
            u.w = (unsigned)p[6] | ((unsigned)p[7] << 16);
            *(uint4v*)(zt + (size_t)(n0 + nl) * DIMC + c0 + oct * 8) = u;
        }
    } else if (bid < 2048) {
        unsigned short* cbt = (unsigned short*)(out + CBT_OFF);
        size_t t = (size_t)(bid - 1024) * 256 + tid;
        float4 a = *(const float4*)(cb + t * 8);
        float4 b = *(const float4*)(cb + t * 8 + 4);
        uint4v u;
        u.x = (unsigned)f2bf(a.x) | ((unsigned)f2bf(a.y) << 16);
        u.y = (unsigned)f2bf(a.z) | ((unsigned)f2bf(a.w) << 16);
        u.z = (unsigned)f2bf(b.x) | ((unsigned)f2bf(b.y) << 16);
        u.w = (unsigned)f2bf(b.z) | ((unsigned)f2bf(b.w) << 16);
        *(uint4v*)(cbt + t * 8) = u;
        if (bid == 1024 && tid == 0) {
            out[LOSS_OFF] = 0.0f;
            out[SCR_OFF] = 0.0f;              // f64 loss accumulator
            out[SCR_OFF + 1] = 0.0f;
            ((unsigned*)out)[TKT_OFF] = 0u;   // ticket
        }
    } else {
        int n = (bid - 2048) * 256 + tid;
        const float* zp = z + (size_t)(n >> 10) * (DIMC * HW) + (n & 1023);
        double s = 0.0;
        for (int c = 0; c < DIMC; ++c) {
            double v = (double)zp[(size_t)c * HW];
            s += v * v;
        }
        out[ZSQ_OFF + n] = (float)s;
    }
}

// --- 2: bf16 MFMA argmin: counted-vmcnt triple-buffer pipeline (R9) --------
// grid (64 row-blocks, 8 slices), 256 threads. Block: 256 rows x 1024 codes.
__global__ __launch_bounds__(256, 2)
void argmin_kernel(float* __restrict__ out) {
    __shared__ __align__(16) unsigned short a_s[3 * 8192];   // 48 KB, 3 bufs
    const unsigned short* zt  = (const unsigned short*)(out + ZT_OFF);
    const unsigned short* cbt = (const unsigned short*)(out + CBT_OFF);
    unsigned* cand = (unsigned*)(out + CAND_OFF);

    int tid = threadIdx.x;
    int lane = tid & 63;
    int wv = tid >> 6;
    int col = lane & 15, qk = lane >> 4;
    int n0 = blockIdx.x * 256;
    int slice = blockIdx.y;

    bf16x8 B[4][8];
    #pragma unroll
    for (int rf = 0; rf < 4; ++rf)
        #pragma unroll
        for (int t = 0; t < 8; ++t)
            B[rf][t] = *(const bf16x8*)(zt + (size_t)(n0 + wv * 64 + rf * 16 + col) * DIMC
                                           + t * 32 + qk * 8);

    int rl2 = lane >> 5;
    int jsl = lane & 31;
    const unsigned short* srcb[4];
    #pragma unroll
    for (int c = 0; c < 4; ++c) {
        int rloc = (wv * 4 + c) * 2 + rl2;
        int src16 = jsl ^ (rloc & 7) ^ ((rloc & 8) >> 1);
        srcb[c] = cbt + ((size_t)slice * 1024 + rloc) * DIMC + src16 * 8;
    }

    unsigned U1[4] = {0, 0, 0, 0}, U2[4] = {0, 0, 0, 0};

    const unsigned sb = (unsigned)((col & 7) ^ ((col & 8) >> 1));
    const unsigned short* aoff[8];
    #pragma unroll
    for (int t = 0; t < 8; ++t)
        aoff[t] = a_s + col * 256 + (((unsigned)(qk + 4 * t)) ^ sb) * 8;

    f32x4 acc[4][2];
    const f32x4 BIASV = (f32x4){131072.0f, 131072.0f, 131072.0f, 131072.0f};

    auto stage = [&](int ch, int dsto /*shorts*/) {
        const size_t off = (size_t)ch * 32 * DIMC;
        unsigned short* dst = a_s + dsto;
        #pragma unroll
        for (int c = 0; c < 4; ++c)
            GLD_LDS16(srcb[c] + off, dst + (wv * 4 + c) * 512);
    };

    auto epi1 = [&](unsigned tb) {
        #pragma unroll
        for (int rf = 0; rf < 4; ++rf)
            #pragma unroll
            for (int r = 0; r < 4; ++r) {
                unsigned bits = __float_as_uint(acc[rf][1][r]);
                unsigned u = (bits & 0xFFFFFF00u) | (tb - (unsigned)(4 + r));
                unsigned lo = umin(u, U1[rf]);
                U1[rf] = umax(u, U1[rf]);
                U2[rf] = umax(lo, U2[rf]);
            }
    };

    auto compute = [&](int bufb, unsigned tb) {
        #pragma unroll
        for (int rf = 0; rf < 4; ++rf) acc[rf][0] = BIASV;
        #pragma unroll
        for (int t = 0; t < 8; ++t) {
            bf16x8 af = *(const bf16x8*)((const char*)aoff[t] + bufb);
            acc[0][0] = __builtin_amdgcn_mfma_f32_16x16x32_bf16(af, B[0][t], acc[0][0], 0, 0, 0);
            acc[1][0] = __builtin_amdgcn_mfma_f32_16x16x32_bf16(af, B[1][t], acc[1][0], 0, 0, 0);
            acc[2][0] = __builtin_amdgcn_mfma_f32_16x16x32_bf16(af, B[2][t], acc[2][0], 0, 0, 0);
            acc[3][0] = __builtin_amdgcn_mfma_f32_16x16x32_bf16(af, B[3][t], acc[3][0], 0, 0, 0);
        }
        #pragma unroll
        for (int rf = 0; rf < 4; ++rf) acc[rf][1] = BIASV;
        #pragma unroll
        for (int t = 0; t < 8; ++t) {
            bf16x8 af = *(const bf16x8*)((const char*)aoff[t] + bufb + 8192);
            acc[0][1] = __builtin_amdgcn_mfma_f32_16x16x32_bf16(af, B[0][t], acc[0][1], 0, 0, 0);
            acc[1][1] = __builtin_amdgcn_mfma_f32_16x16x32_bf16(af, B[1][t], acc[1][1], 0, 0, 0);
            acc[2][1] = __builtin_amdgcn_mfma_f32_16x16x32_bf16(af, B[2][t], acc[2][1], 0, 0, 0);
            acc[3][1] = __builtin_amdgcn_mfma_f32_16x16x32_bf16(af, B[3][t], acc[3][1], 0, 0, 0);
            {
                const int q0 = 2 * t, q1 = 2 * t + 1;
                const int rfA = q0 >> 2, rA = q0 & 3;
                const int rfB = q1 >> 2, rB = q1 & 3;
                unsigned bitsA = __float_as_uint(acc[rfA][0][rA]);
                unsigned uA = (bitsA & 0xFFFFFF00u) | (tb - (unsigned)rA);
                unsigned loA = umin(uA, U1[rfA]);
                U1[rfA] = umax(uA, U1[rfA]);
                U2[rfA] = umax(loA, U2[rfA]);
                unsigned bitsB = __float_as_uint(acc[rfB][0][rB]);
                unsigned uB = (bitsB & 0xFFFFFF00u) | (tb - (unsigned)rB);
                unsigned loB = umin(uB, U1[rfB]);
                U1[rfB] = umax(uB, U1[rfB]);
                U2[rfB] = umax(loB, U2[rfB]);
            }
        }
    };

#define CHUNK_SYNC(N)                                          \
    asm volatile("s_waitcnt vmcnt(" #N ")" ::: "memory");      \
    __builtin_amdgcn_s_barrier();                              \
    __builtin_amdgcn_sched_barrier(0);

    stage(0, 0);
    stage(1, 8192);

    CHUNK_SYNC(4)
    stage(2, 16384);
    compute(0, 255u);

    #pragma unroll 1
    for (int k = 0; k < 10; ++k) {
        const int c1 = 3 * k + 1;
        const unsigned tb = 255u - ((unsigned)c1 << 3);
        CHUNK_SYNC(4)
        stage(c1 + 2, 0);
        epi1(tb + 8u);
        compute(16384, tb);
        CHUNK_SYNC(4)
        stage(c1 + 3, 8192);
        epi1(tb);
        compute(32768, tb - 8u);
        CHUNK_SYNC(4)
        if (k < 9) stage(c1 + 4, 16384);
        epi1(tb - 8u);
        compute(0, tb - 16u);
    }
    CHUNK_SYNC(0)
    epi1(255u - (30u << 3));
    compute(16384, 255u - (31u << 3));
    epi1(255u - (31u << 3));
#undef CHUNK_SYNC

    #pragma unroll
    for (int rf = 0; rf < 4; ++rf) {
        unsigned t1 = 255u - (U1[rf] & 255u);
        unsigned c1 = (t1 >> 3) * 32 + ((t1 >> 2) & 1) * 16 + qk * 4 + (t1 & 3);
        unsigned x1 = ((((U1[rf] & 0xFFFFFF00u) - 0x47000000u) >> 3) << 10) | (1023u - c1);
        unsigned t2 = 255u - (U2[rf] & 255u);
        unsigned c2 = (t2 >> 3) * 32 + ((t2 >> 2) & 1) * 16 + qk * 4 + (t2 & 3);
        unsigned x2 = ((((U2[rf] & 0xFFFFFF00u) - 0x47000000u) >> 3) << 10) | (1023u - c2);
        unsigned p1 = __shfl_xor(x1, 16);
        unsigned p2 = __shfl_xor(x2, 16);
        unsigned s1 = umax(x1, p1), tm = umin(x1, p1);
        unsigned ym = umax(x2, p2), s4 = umin(x2, p2);
        unsigned s2 = umax(tm, ym), s3 = umin(tm, ym);
        unsigned r1 = umax(s1, __shfl_xor(s4, 32));
        unsigned r2 = umax(s2, __shfl_xor(s3, 32));
        unsigned r3 = umax(s3, __shfl_xor(s2, 32));
        unsigned r4 = umax(s4, __shfl_xor(s1, 32));
        if (qk == 0) {
            int row = wv * 64 + rf * 16 + col;
            uint4v cw; cw.x = r1; cw.y = r2; cw.z = r3; cw.w = r4;
            *(uint4v*)(cand + ((size_t)slice * NROWS + n0 + row) * 4) = cw;
        }
    }
}

// --- 3: prune + fp64 re-score + fused loss (v2: 512 blocks x 32 rows) ------
// z staged once, coalesced (128B segments), f32 LDS [row][264] XOR-quad swz.
__global__ __launch_bounds__(256, 4)
void fixup_kernel(const float* __restrict__ z, const float* __restrict__ cb,
                  float* __restrict__ out) {
    __shared__ float zs[32 * 264];       // [row][c^((row>>2)<<2)], pad 8
    __shared__ float zsq_s[32];
    __shared__ unsigned qmx[32];
    __shared__ float dsc[32 * 33];       // [row][j]
    __shared__ unsigned cds[32 * 33];
    __shared__ unsigned bcode[32];
    __shared__ double lred[4];
    int tid = threadIdx.x;
    int n0 = blockIdx.x * 32;
    const float* zb = z + (size_t)(n0 >> 10) * (DIMC * HW) + (n0 & 1023);

    // stage z tile: thread = (row-quad q, channel-low cq); 128B segments
    {
        int q = tid & 7, cq = tid >> 3;
        #pragma unroll
        for (int i = 0; i < 8; ++i) {
            int c = cq + i * 32;
            float4 v = *(const float4*)(zb + (size_t)c * HW + q * 4);
            int sc = c ^ (q << 2);       // XOR key = row>>2 = q (all 4 rows)
            zs[(q * 4 + 0) * 264 + sc] = v.x;
            zs[(q * 4 + 1) * 264 + sc] = v.y;
            zs[(q * 4 + 2) * 264 + sc] = v.z;
            zs[(q * 4 + 3) * 264 + sc] = v.w;
        }
    }
    if (tid < 32) { zsq_s[tid] = out[ZSQ_OFF + n0 + tid]; qmx[tid] = 0; }

    // candidate words for all 4 batches (coalesced 128B segments)
    int j = tid >> 3, r = tid & 7;
    unsigned w[4];
    #pragma unroll
    for (int b = 0; b < 4; ++b)
        w[b] = ((const unsigned*)(out + CAND_OFF))
               [(((size_t)(j >> 2)) * NROWS + n0 + b * 8 + r) * 4 + (j & 3)];
    __syncthreads();
    #pragma unroll
    for (int b = 0; b < 4; ++b)
        atomicMax(&qmx[b * 8 + r], w[b] >> 10);
    __syncthreads();

    // 4 batches of the validated 8-row x 32-cand fp64 re-score
    #pragma unroll 1
    for (int b = 0; b < 4; ++b) {
        int row = b * 8 + r;
        unsigned qv = w[b] >> 10;
        unsigned code = (unsigned)((j >> 2) * 1024) + 1023u - (w[b] & 1023u);
        bool live = (qv + PRUNE_T >= qmx[row]);
        float d = FLT_MAX;
        if (live) {
            const float* e = cb + (size_t)code * DIMC;
            const float* zrow = zs + row * 264;
            const int xr = (row >> 2) << 2;
            double a0 = 0.0, a1 = 0.0, a2 = 0.0, a3 = 0.0;
            for (int c = 0; c < DIMC; c += 16) {
                float4 e0 = *(const float4*)(e + c);
                float4 e1 = *(const float4*)(e + c + 4);
                float4 e2 = *(const float4*)(e + c + 8);
                float4 e3 = *(const float4*)(e + c + 12);
                float4 z0 = *(const float4*)(zrow + ((c) ^ xr));
                float4 z1 = *(const float4*)(zrow + ((c + 4) ^ xr));
                float4 z2 = *(const float4*)(zrow + ((c + 8) ^ xr));
                float4 z3 = *(const float4*)(zrow + ((c + 12) ^ xr));
                a0 += (double)z0.x * (double)e0.x + (double)z0.y * (double)e0.y
                    + (double)z0.z * (double)e0.z + (double)z0.w * (double)e0.w;
                a1 += (double)z1.x * (double)e1.x + (double)z1.y * (double)e1.y
                    + (double)z1.z * (double)e1.z + (double)z1.w * (double)e1.w;
                a2 += (double)z2.x * (double)e2.x + (double)z2.y * (double)e2.y
                    + (double)z2.z * (double)e2.z + (double)z2.w * (double)e2.w;
                a3 += (double)z3.x * (double)e3.x + (double)z3.y * (double)e3.y
                    + (double)z3.z * (double)e3.z + (double)z3.w * (double)e3.w;
            }
            d = fmaf(-2.0f, (float)((a0 + a1) + (a2 + a3)), zsq_s[row]);
        }
        dsc[row * 33 + j] = d;
        cds[row * 33 + j] = code;
    }
    __syncthreads();
    if (tid < 32) {
        float bd = FLT_MAX; unsigned bi = 0xffffffffu;
        for (int jj = 0; jj < 32; ++jj) {
            float dv = dsc[tid * 33 + jj];
            unsigned k = cds[tid * 33 + jj];
            if (dv < bd || (dv == bd && k < bi)) { bd = dv; bi = k; }
        }
        out[IDX_OFF + n0 + tid] = (float)bi;
        bcode[tid] = bi;
    }
    __syncthreads();

    // fused loss on the staged tile: thread = (row, c-32-group), f64
    {
        int row = tid & 31, cg = tid >> 5;
        const float* zrow = zs + row * 264;
        const int xr = (row >> 2) << 2;
        const float* e = cb + (size_t)bcode[row] * DIMC;
        double lacc = 0.0;
        #pragma unroll
        for (int i = 0; i < 8; ++i) {
            int c = cg * 32 + (((i + row) & 7) << 2);   // staggered quads
            float4 ev = *(const float4*)(e + c);
            float4 zv = *(const float4*)(zrow + (c ^ xr));
            double d0 = (double)ev.x - (double)zv.x;
            double d1 = (double)ev.y - (double)zv.y;
            double d2 = (double)ev.z - (double)zv.z;
            double d3 = (double)ev.w - (double)zv.w;
            lacc += d0 * d0 + d1 * d1 + d2 * d2 + d3 * d3;
        }
        #pragma unroll
        for (int off = 32; off; off >>= 1) lacc += __shfl_down(lacc, off);
        if ((tid & 63) == 0) lred[tid >> 6] = lacc;
    }
    __syncthreads();
    if (tid == 0) {
        double part = (lred[0] + lred[1]) + (lred[2] + lred[3]);
        atomicAdd((double*)(out + SCR_OFF), part);
        asm volatile("s_waitcnt vmcnt(0)" ::: "memory");   // order add < ticket
        unsigned t = atomicAdd(((unsigned*)out) + TKT_OFF, 1u);
        if (t == 511u) {   // last block: all SCR adds ordered at coherence pt
            double tot = atomicAdd((double*)(out + SCR_OFF), 0.0);
            out[LOSS_OFF] = (float)(tot * (1.25 / 4194304.0));
        }
    }
}

// --- 4: z_q pure gather->scatter: 1024 blocks x 256 thr, 16 rows/block -----
__global__ __launch_bounds__(256)
void zq_kernel(const float* __restrict__ z, const float* __restrict__ cb,
               float* __restrict__ out) {
    __shared__ float lds[16 * 260];   // [r][c], pad 4 (16B-aligned rows)
    int tid = threadIdx.x;
    int n0 = blockIdx.x * 16;
    {   // gather 16 codebook rows: direct b128 LDS writes
        int rr = tid >> 4, q = tid & 15;
        int code = (int)out[IDX_OFF + n0 + rr];
        const float* e = cb + (size_t)code * DIMC;
        #pragma unroll
        for (int jj = 0; jj < 4; ++jj) {
            int c = q * 4 + jj * 64;
            *(float4*)(lds + rr * 260 + c) = *(const float4*)(e + c);
        }
    }
    __syncthreads();
    // scatter: thread = (channel g, row-quad rq); column reads are 2-way free
    int g = tid >> 2, rq = tid & 3;
    int b = n0 >> 10, hw0 = n0 & 1023;
    const size_t base = (size_t)b * (DIMC * HW) + hw0 + rq * 4;
    #pragma unroll
    for (int i = 0; i < 4; ++i) {
        int c = g + i * 64;
        float4 v;
        v.x = lds[(rq * 4 + 0) * 260 + c];
        v.y = lds[(rq * 4 + 1) * 260 + c];
        v.z = lds[(rq * 4 + 2) * 260 + c];
        v.w = lds[(rq * 4 + 3) * 260 + c];
        *(float4*)(out + base + (size_t)c * HW) = v;
    }
}

extern "C" void kernel_launch(void* const* d_in, const int* in_sizes, int n_in,
                              void* d_out, int out_size, void* d_ws, size_t ws_size,
                              hipStream_t stream) {
    const float* z  = (const float*)d_in[0];
    const float* cb = (const float*)d_in[1];
    float* out = (float*)d_out;

    prep_kernel<<<2112, 256, 0, stream>>>(z, cb, out);
    argmin_kernel<<<dim3(64, NSLICE), 256, 0, stream>>>(out);
    fixup_kernel<<<512, 256, 0, stream>>>(z, cb, out);
    zq_kernel<<<1024, 256, 0, stream>>>(z, cb, out);
}